// Round 14
// baseline (68.126 us; speedup 1.0000x reference)
//
#include <hip/hip_runtime.h>
#include <math.h>

// Problem constants
#define NB 4
#define NC 2048
#define NH 8
#define NK 128
#define NG 255          // a-grid points per (b,h)

// exp2-domain logit scale: log2(e)/sqrt(128)
#define A2SCALE (1.4426950408889634f * 0.08838834764831845f)

typedef __attribute__((ext_vector_type(8))) short bf16x8;
typedef __attribute__((ext_vector_type(4))) float f32x4;

// ---------------- ws layout (float offsets) ----------------
// wspart [4][2048]           @ 0       (8192) dead after prep2 ->
//   mm   [32][2]             @ 0       amin,hstep per bh (written k_c)
// W2 f32 [8][128][128]       @ 8192    (131072) live until k_n
// qs     [32][2048]          @ 139264
// ks     [32][2048]          @ 204800
// X_bf   [4b][64ig][8nt][64lane][8j] bf16 @ 270336 (1,048,576 ushort = 524,288 f)
// partsC [32][4sl][255][128] @ 4464640 (4,177,920) -> slice0 becomes tablef
// total 8,642,560 floats (< R0-proven 8,652,864)
// parts_z [32][4][255] lives in d_out (overwritten by k_eval)
#define OFF_MM  0
#define OFF_W2  8192
#define OFF_QS  139264
#define OFF_KS  204800
#define OFF_XB  270336
#define OFF_PN  4464640

__device__ static inline float exp2_hw(float x) {
#if __has_builtin(__builtin_amdgcn_exp2f)
    return __builtin_amdgcn_exp2f(x);
#else
    float r;
    asm volatile("v_exp_f32 %0, %1\n\ts_nop 1" : "=v"(r) : "v"(x));
    return r;
#endif
}

__device__ static inline unsigned cvtpk(float lo, float hi) {
    unsigned r;
    asm("v_cvt_pk_bf16_f32 %0, %1, %2" : "=v"(r) : "v"(lo), "v"(hi));
    return r;
}

__device__ static inline bf16x8 pack8(float4 a, float4 b) {
    union { unsigned u[4]; bf16x8 v; } r;
    r.u[0] = cvtpk(a.x, a.y);
    r.u[1] = cvtpk(a.z, a.w);
    r.u[2] = cvtpk(b.x, b.y);
    r.u[3] = cvtpk(b.z, b.w);
    return r.v;
}

// 8 exps of (a*k + negM) packed to a bf16x8 A-fragment; accumulates sum in z
__device__ static inline bf16x8 pexp8s(float4 ka, float4 kb, float a, float negM,
                                       float& z) {
    float e0 = exp2_hw(fmaf(a, ka.x, negM));
    float e1 = exp2_hw(fmaf(a, ka.y, negM));
    float e2 = exp2_hw(fmaf(a, ka.z, negM));
    float e3 = exp2_hw(fmaf(a, ka.w, negM));
    float e4 = exp2_hw(fmaf(a, kb.x, negM));
    float e5 = exp2_hw(fmaf(a, kb.y, negM));
    float e6 = exp2_hw(fmaf(a, kb.z, negM));
    float e7 = exp2_hw(fmaf(a, kb.w, negM));
    z += ((e0 + e1) + (e2 + e3)) + ((e4 + e5) + (e6 + e7));
    union { unsigned u[4]; bf16x8 v; } r;
    r.u[0] = cvtpk(e0, e1);
    r.u[1] = cvtpk(e2, e3);
    r.u[2] = cvtpk(e4, e5);
    r.u[3] = cvtpk(e6, e7);
    return r.v;
}

// ---- prep1: (blk<64) wsum ; (blk>=64) W2 ----  grid 576 x 256 (R13-identical)
__global__ __launch_bounds__(256) void k_prep1(const float* __restrict__ Wq,
                                               const float* __restrict__ Wk,
                                               const float* __restrict__ Wv,
                                               const float* __restrict__ Wo,
                                               float* __restrict__ wspart,
                                               float* __restrict__ W2) {
    int blk = blockIdx.x;
    int tid = threadIdx.x;
    __shared__ float sh[256];
    if (blk < 64) {
        int which = blk >> 5, h = (blk >> 2) & 7, eq = blk & 3;
        const float* W = which ? Wk : Wq;
        int m = tid & 127, part = tid >> 7;
        const float* base = W + (h * 128 + eq * 32 + part * 16) * 128 + m;
        float s = 0.f;
#pragma unroll
        for (int e = 0; e < 16; ++e) s += base[e * 128];
        if (part) sh[m] = s;
        __syncthreads();
        if (!part) wspart[eq * 2048 + which * 1024 + h * 128 + m] = s + sh[m];
    } else {
        int idx = blk - 64;                    // 0..511
        int h = idx >> 6;
        int kl = tid >> 7;                     // 0..1
        int kk = (idx & 63) * 2 + kl;
        int m = tid & 127;
        float* wo_s = sh;                      // [2][128]
        wo_s[kl * 128 + m] = Wo[kk * 1024 + h * 128 + m];
        __syncthreads();
        const float* base = Wv + (h * 128) * 128 + m;
        const float* wrow = &wo_s[kl * 128];
        float s = 0.f;
#pragma unroll 4
        for (int e = 0; e < 128; ++e) s += base[e * 128] * wrow[e];
        W2[(h * 128 + kk) * 128 + m] = s;
    }
}

// ---- prep2: qs/ks + X_bf frag emit ----  grid 256 x 256 (u-GEMM deleted)
// Block handles 32 consecutive rows of one b = exactly one ig chunk.
__global__ __launch_bounds__(256) void k_prep2(const float* __restrict__ x,
                                               const float* __restrict__ wspart,
                                               float* __restrict__ qs,
                                               float* __restrict__ ks,
                                               unsigned short* __restrict__ xbf) {
    __shared__ float xs[32][129];
    __shared__ float wsum[2048];
    int tid = threadIdx.x;
    int blk = blockIdx.x;
    for (int j = tid; j < 2048; j += 256)
        wsum[j] = wspart[j] + wspart[2048 + j] + wspart[4096 + j] + wspart[6144 + j];
    int row0 = blk * 32;
    for (int j = tid; j < 32 * 128; j += 256) {
        int r = j >> 7, m = j & 127;
        xs[r][m] = x[(size_t)(row0 + r) * 128 + m];
    }
    __syncthreads();
    // qs/ks dot products (R13-identical)
#pragma unroll
    for (int jj = 0; jj < 2; ++jj) {
        int o = tid + 256 * jj;
        int r = o & 31;
        int q = o >> 5;
        int which = q >> 3, h = q & 7;
        const float* wrow = &wsum[which * 1024 + h * 128];
        const float* xrow = &xs[r][0];
        float s = 0.f;
#pragma unroll 4
        for (int m = 0; m < 128; ++m) s += xrow[m] * wrow[m];
        int row = row0 + r, b = row >> 11, t = row & 2047;
        float* dst = which ? ks : qs;
        dst[(b * 8 + h) * 2048 + t] = s;
    }
    // X_bf B-frags for this (b, ig): element (i = ig*32 + l4*8 + j, m = nt*16 + l15)
    {
        int b = row0 >> 11;
        int ig = (row0 >> 5) & 63;
        unsigned short* xb = xbf + (size_t)(b * 64 + ig) * 4096;
#pragma unroll
        for (int qq = 0; qq < 2; ++qq) {
            int q = tid + qq * 256;            // 0..511
            int nt = q >> 6, lane = q & 63;
            int l4 = lane >> 4, m = nt * 16 + (lane & 15);
            int ib = l4 * 8;
            union { unsigned u[4]; uint4 v; } pk;
            pk.u[0] = cvtpk(xs[ib + 0][m], xs[ib + 1][m]);
            pk.u[1] = cvtpk(xs[ib + 2][m], xs[ib + 3][m]);
            pk.u[2] = cvtpk(xs[ib + 4][m], xs[ib + 5][m]);
            pk.u[3] = cvtpk(xs[ib + 6][m], xs[ib + 7][m]);
            *(uint4*)&xb[(size_t)nt * 512 + lane * 8] = pk.v;
        }
    }
}

// ---- k_c: C partials = E @ X on the a-grid, per (bh, 64-g tile, i-slice) ----
// grid 512 x 256 (R13 k_table structure; B-source = X_bf[b], shared across h)
__global__ __launch_bounds__(256, 2) void k_c(const float* __restrict__ qs,
                                              const float* __restrict__ ks,
                                              const unsigned short* __restrict__ xbf,
                                              float* __restrict__ pC,
                                              float* __restrict__ pz,
                                              float* __restrict__ mm) {
    int L = blockIdx.x;
    int xcd = L & 7, s = L >> 3;
    int bh = xcd * 4 + (s >> 4);
    int rem = s & 15;
    int gt = rem >> 2, sl = rem & 3;
    int b = bh >> 3;
    int tid = threadIdx.x;
    int lane = tid & 63, wid = tid >> 6;
    int l15 = lane & 15, l4 = lane >> 4;

    __shared__ float kss[2048];
    __shared__ __align__(16) unsigned short u_l[3][4096];
    __shared__ float red[8];

    // ---- phase 1: qs min/max -> amin, hstep ----
    for (int j = tid; j < 512; j += 256)
        ((float4*)kss)[j] = ((const float4*)(qs + bh * 2048))[j];
    __syncthreads();
    float mn = 1e30f, mx = -1e30f;
    {
        const float4* ka = (const float4*)kss;
#pragma unroll
        for (int jj = 0; jj < 2; ++jj) {
            float4 v = ka[tid + jj * 256];
            mn = fminf(mn, fminf(fminf(v.x, v.y), fminf(v.z, v.w)));
            mx = fmaxf(mx, fmaxf(fmaxf(v.x, v.y), fmaxf(v.z, v.w)));
        }
#pragma unroll
        for (int off = 32; off; off >>= 1) {
            mn = fminf(mn, __shfl_xor(mn, off));
            mx = fmaxf(mx, __shfl_xor(mx, off));
        }
        if (!lane) { red[wid] = mn; red[4 + wid] = mx; }
    }
    __syncthreads();
    mn = fminf(fminf(red[0], red[1]), fminf(red[2], red[3]));
    mx = fmaxf(fmaxf(red[4], red[5]), fmaxf(red[6], red[7]));
    float amin = mn * A2SCALE;
    float hstep = fmaxf((mx * A2SCALE - amin), 1e-6f) * (1.f / (NG - 1));
    if (tid == 0) { mm[bh * 2] = amin; mm[bh * 2 + 1] = hstep; }
    __syncthreads();

    // ---- phase 2: ks stage + global min/max ----
    for (int j = tid; j < 512; j += 256)
        ((float4*)kss)[j] = ((const float4*)(ks + bh * 2048))[j];
    __syncthreads();
    mn = 1e30f; mx = -1e30f;
    {
        const float4* ka = (const float4*)kss;
#pragma unroll
        for (int jj = 0; jj < 2; ++jj) {
            float4 v = ka[tid + jj * 256];
            mn = fminf(mn, fminf(fminf(v.x, v.y), fminf(v.z, v.w)));
            mx = fmaxf(mx, fmaxf(fmaxf(v.x, v.y), fmaxf(v.z, v.w)));
        }
#pragma unroll
        for (int off = 32; off; off >>= 1) {
            mn = fminf(mn, __shfl_xor(mn, off));
            mx = fmaxf(mx, __shfl_xor(mx, off));
        }
        if (!lane) { red[wid] = mn; red[4 + wid] = mx; }
    }
    __syncthreads();
    mn = fminf(fminf(red[0], red[1]), fminf(red[2], red[3]));
    mx = fmaxf(fmaxf(red[4], red[5]), fmaxf(red[6], red[7]));

    int grow = gt * 64 + wid * 16 + l15;
    float a = fmaf((float)grow, hstep, amin);
    float negM = -(a > 0.f ? a * mx : a * mn);
    float zacc = 0.f;

    const unsigned short* gxb = xbf + (size_t)b * 262144 + (size_t)sl * 65536;

    f32x4 acc[8];
#pragma unroll
    for (int n = 0; n < 8; ++n) acc[n] = (f32x4)0.f;

#define DMA(cnv, buf) do {                                                     \
    const unsigned short* src_ = gxb + (size_t)(cnv) * 4096;                   \
    _Pragma("unroll")                                                          \
    for (int q_ = 0; q_ < 2; ++q_) {                                           \
        int seg_ = q_ * 4 + wid;                                               \
        __builtin_amdgcn_global_load_lds(                                      \
            (const __attribute__((address_space(1))) unsigned int*)(src_ + seg_ * 512 + lane * 8), \
            (__attribute__((address_space(3))) unsigned int*)(&u_l[buf][seg_ * 512]),              \
            16, 0, 0);                                                         \
    }                                                                          \
} while (0)

    DMA(0, 0);
    DMA(1, 1);
    for (int cn = 0; cn < 15; ++cn) {
        int cur = cn % 3;
        int ib = sl * 512 + cn * 32;
        float4 ka = *(const float4*)&kss[ib + l4 * 8];
        float4 kb = *(const float4*)&kss[ib + l4 * 8 + 4];
        bf16x8 pf = pexp8s(ka, kb, a, negM, zacc);

        asm volatile("s_waitcnt vmcnt(2)" ::: "memory");
        __builtin_amdgcn_sched_barrier(0);
        __builtin_amdgcn_s_barrier();
        __builtin_amdgcn_sched_barrier(0);
        if (cn + 2 <= 15) DMA(cn + 2, (cn + 2) % 3);
        __builtin_amdgcn_sched_barrier(0);

        __builtin_amdgcn_s_setprio(1);
#pragma unroll
        for (int n = 0; n < 8; ++n) {
            bf16x8 uf = *(const bf16x8*)&u_l[cur][n * 512 + lane * 8];
            acc[n] = __builtin_amdgcn_mfma_f32_16x16x32_bf16(pf, uf, acc[n], 0, 0, 0);
        }
        __builtin_amdgcn_s_setprio(0);
    }
    {   // tail: chunk 15 (buf 15%3 == 0)
        int ib = sl * 512 + 15 * 32;
        float4 ka = *(const float4*)&kss[ib + l4 * 8];
        float4 kb = *(const float4*)&kss[ib + l4 * 8 + 4];
        bf16x8 pf = pexp8s(ka, kb, a, negM, zacc);
        asm volatile("s_waitcnt vmcnt(0)" ::: "memory");
        __builtin_amdgcn_sched_barrier(0);
        __builtin_amdgcn_s_barrier();
        __builtin_amdgcn_sched_barrier(0);
#pragma unroll
        for (int n = 0; n < 8; ++n) {
            bf16x8 uf = *(const bf16x8*)&u_l[0][n * 512 + lane * 8];
            acc[n] = __builtin_amdgcn_mfma_f32_16x16x32_bf16(pf, uf, acc[n], 0, 0, 0);
        }
    }
#undef DMA

    zacc += __shfl_xor(zacc, 16);
    zacc += __shfl_xor(zacc, 32);
    if (l4 == 0 && grow < NG)
        pz[(bh * 4 + sl) * NG + grow] = zacc;

#pragma unroll
    for (int r = 0; r < 4; ++r) {
        int g = gt * 64 + wid * 16 + l4 * 4 + r;
        if (g < NG) {
            float* row = pC + ((size_t)(bh * 4 + sl) * NG + g) * 128;
#pragma unroll
            for (int n = 0; n < 8; ++n)
                row[n * 16 + l15] = acc[n][r];
        }
    }
}

// ---- k_n: tablef[bh][g][kk] = (1/z) sum_m (sum_sl C)[g][m] * W2[h][kk][m] ----
// grid 128 x 256: (bh, gt). In-place overlay of C slice 0 (barrier-separated).
__global__ __launch_bounds__(256) void k_n(float* __restrict__ pC,
                                           const float* __restrict__ pz,
                                           const float* __restrict__ W2) {
    int L = blockIdx.x;
    int bh = L >> 2, gt = L & 3;
    int h = bh & 7;
    int tid = threadIdx.x;
    int lane = tid & 63, wid = tid >> 6;
    int wr = wid >> 1, wc = wid & 1;
    int l15 = lane & 15, l4 = lane >> 4;

    const float* w2h = W2 + h * 16384;
    const size_t slo = (size_t)NG * 128;   // slice stride
    const size_t cb = (size_t)(bh * 4) * NG * 128;

    f32x4 acc[2][4];
#pragma unroll
    for (int mg = 0; mg < 2; ++mg)
#pragma unroll
        for (int nt = 0; nt < 4; ++nt) acc[mg][nt] = (f32x4)0.f;

#pragma unroll
    for (int kq = 0; kq < 4; ++kq) {
        bf16x8 af[2], bfr[4];
#pragma unroll
        for (int mg = 0; mg < 2; ++mg) {
            int g = gt * 64 + wr * 32 + mg * 16 + l15;
            size_t base = cb + (size_t)g * 128 + kq * 32 + l4 * 8;
            float4 sa = *(const float4*)&pC[base];
            float4 sb = *(const float4*)&pC[base + 4];
#pragma unroll
            for (int sl = 1; sl < 4; ++sl) {
                float4 ta = *(const float4*)&pC[base + sl * slo];
                float4 tb = *(const float4*)&pC[base + sl * slo + 4];
                sa.x += ta.x; sa.y += ta.y; sa.z += ta.z; sa.w += ta.w;
                sb.x += tb.x; sb.y += tb.y; sb.z += tb.z; sb.w += tb.w;
            }
            af[mg] = pack8(sa, sb);
        }
#pragma unroll
        for (int nt = 0; nt < 4; ++nt) {
            int kk = wc * 64 + nt * 16 + l15;
            const float* src = w2h + kk * 128 + kq * 32 + l4 * 8;
            bfr[nt] = pack8(*(const float4*)src, *(const float4*)(src + 4));
        }
#pragma unroll
        for (int mg = 0; mg < 2; ++mg)
#pragma unroll
            for (int nt = 0; nt < 4; ++nt)
                acc[mg][nt] = __builtin_amdgcn_mfma_f32_16x16x32_bf16(
                    af[mg], bfr[nt], acc[mg][nt], 0, 0, 0);
    }

    __syncthreads();   // ALL C reads done before slice-0 overwrite

#pragma unroll
    for (int mg = 0; mg < 2; ++mg) {
#pragma unroll
        for (int r = 0; r < 4; ++r) {
            int g = gt * 64 + wr * 32 + mg * 16 + l4 * 4 + r;
            if (g < NG) {
                float z = pz[(bh * 4 + 0) * NG + g] + pz[(bh * 4 + 1) * NG + g] +
                          pz[(bh * 4 + 2) * NG + g] + pz[(bh * 4 + 3) * NG + g];
                float zinv = 1.f / z;
                float* row = pC + cb + (size_t)g * 128;
#pragma unroll
                for (int nt = 0; nt < 4; ++nt)
                    row[wc * 64 + nt * 16 + l15] = acc[mg][nt][r] * zinv;
            }
        }
    }
}

// ---- k_eval: y[b][t][kk] = bo[kk] + sum_h Lagrange4(tablef[bh], p(a_bh,t)) ----
// grid 512 x 256 (R13-identical)
__global__ __launch_bounds__(256) void k_eval(const float* __restrict__ qs,
                                              const float* __restrict__ tablef,
                                              const float* __restrict__ mm,
                                              const float* __restrict__ bo,
                                              float* __restrict__ y) {
    int blk = blockIdx.x;
    int b = blk >> 7;
    int t = (blk & 127) * 16 + (threadIdx.x >> 4);
    int kk0 = (threadIdx.x & 15) * 8;

    float acc[8];
#pragma unroll
    for (int j = 0; j < 8; ++j) acc[j] = bo[kk0 + j];

#pragma unroll
    for (int h = 0; h < 8; ++h) {
        int bh = b * 8 + h;
        float a = qs[bh * 2048 + t] * A2SCALE;
        float amin = mm[bh * 2], hs = mm[bh * 2 + 1];
        float p = (a - amin) / hs;
        int g1 = (int)p;
        g1 = g1 < 1 ? 1 : (g1 > NG - 3 ? NG - 3 : g1);
        float u = p - (float)g1;
        float um1 = u - 1.f, um2 = u - 2.f, up1 = u + 1.f;
        float w0 = -u * um1 * um2 * (1.f / 6.f);
        float w1 = up1 * um1 * um2 * 0.5f;
        float w2 = -up1 * u * um2 * 0.5f;
        float w3 = up1 * u * um1 * (1.f / 6.f);
        const float* base = tablef + ((size_t)(bh * 4) * NG + (g1 - 1)) * 128 + kk0;
#pragma unroll
        for (int v = 0; v < 2; ++v) {
            float4 r0 = *(const float4*)(base + v * 4);
            float4 r1 = *(const float4*)(base + 128 + v * 4);
            float4 r2 = *(const float4*)(base + 256 + v * 4);
            float4 r3 = *(const float4*)(base + 384 + v * 4);
            acc[v * 4 + 0] += w0 * r0.x + w1 * r1.x + w2 * r2.x + w3 * r3.x;
            acc[v * 4 + 1] += w0 * r0.y + w1 * r1.y + w2 * r2.y + w3 * r3.y;
            acc[v * 4 + 2] += w0 * r0.z + w1 * r1.z + w2 * r2.z + w3 * r3.z;
            acc[v * 4 + 3] += w0 * r0.w + w1 * r1.w + w2 * r2.w + w3 * r3.w;
        }
    }
    float* yp = y + ((size_t)b * 2048 + t) * 128 + kk0;
    *(float4*)yp = make_float4(acc[0], acc[1], acc[2], acc[3]);
    *(float4*)(yp + 4) = make_float4(acc[4], acc[5], acc[6], acc[7]);
}

extern "C" void kernel_launch(void* const* d_in, const int* in_sizes, int n_in,
                              void* d_out, int out_size, void* d_ws, size_t ws_size,
                              hipStream_t stream) {
    const float* x  = (const float*)d_in[0];
    const float* Wq = (const float*)d_in[1];
    const float* Wk = (const float*)d_in[2];
    const float* Wv = (const float*)d_in[3];
    const float* Wo = (const float*)d_in[4];
    const float* bo = (const float*)d_in[5];
    float* y  = (float*)d_out;
    float* ws = (float*)d_ws;
    (void)in_sizes; (void)n_in; (void)out_size; (void)ws_size;

    unsigned short* xbf = (unsigned short*)(ws + OFF_XB);
    float* pC = ws + OFF_PN;
    float* pz = y;             // scratch in d_out; overwritten by k_eval
    float* mm = ws + OFF_MM;   // dead-wspart region

    k_prep1<<<576, 256, 0, stream>>>(Wq, Wk, Wv, Wo, ws, ws + OFF_W2);
    k_prep2<<<256, 256, 0, stream>>>(x, ws, ws + OFF_QS, ws + OFF_KS, xbf);
    k_c<<<512, 256, 0, stream>>>(ws + OFF_QS, ws + OFF_KS, xbf, pC, pz, mm);
    k_n<<<128, 256, 0, stream>>>(pC, pz, ws + OFF_W2);
    k_eval<<<512, 256, 0, stream>>>(ws + OFF_QS, pC, mm, bo, y);
}